// Round 2
// baseline (1407.927 us; speedup 1.0000x reference)
//
#include <hip/hip_runtime.h>
#include <math.h>

// FuzzyAttention: V = softmax(scale * (S + 0.5*sigmoid(S)) with causal mask) @ values
// S = Q K^T, scale = 1/sqrt(64). Shapes: Q,K,V,out = [B=2, L=2048, H=16, E=64] f32.
// Causal mask is the fixed triu(k=1) mask -> computed analytically, mask input ignored.

constexpr int Bc  = 2;
constexpr int Lc  = 2048;
constexpr int Hc  = 16;
constexpr int Ec  = 64;
constexpr int BM  = 64;              // q rows per tile
constexpr int BN  = 64;              // kv rows per tile
constexpr int NQT = Lc / BM;         // 32 q-tiles
constexpr int ROW_STRIDE = Hc * Ec;  // 1024 floats between consecutive l
constexpr int KP = Ec + 4;           // padded K/V LDS row: 68 floats -> conflict-free staging
constexpr float FUZZ_DELTA = 0.5f;
constexpr float SM_SCALE   = 0.125f; // 1/sqrt(64)

__global__ __launch_bounds__(256, 2)
void fuzzy_attn_f32(const float* __restrict__ Qp,
                    const float* __restrict__ Kp,
                    const float* __restrict__ Vp,
                    float* __restrict__ Op) {
    __shared__ float kt[BN][KP];       // K tile  (hot reads are wave-broadcast)
    __shared__ float vt[BN][KP];       // V tile  (hot reads are wave-broadcast)
    __shared__ float pt[BM][BN + 1];   // score tile, +1 pad -> (m+n)%32 banks

    // ---- XCD-aware decode: all 32 q-tiles of one (b,h) land on one XCD ----
    // Linear block id round-robins over 8 XCDs (id % 8). Put bh = grp*8 + xcd so
    // each XCD holds 4 heads' K/V (4 MB f32) in its 4 MB L2. Long q-tiles first.
    const int id  = blockIdx.x;        // 0..1023
    const int xcd = id & 7;
    const int k5  = id >> 3;           // 0..127
    const int grp = k5 >> 5;           // 0..3
    const int qt  = (NQT - 1) - (k5 & 31);   // 31..0 (long blocks launch first)
    const int bh  = grp * 8 + xcd;     // 0..31
    const int b   = bh >> 4;           // H = 16
    const int h   = bh & 15;

    const int tid = threadIdx.x;
    const int m   = tid & 63;          // query row within tile
    const int q4  = tid >> 6;          // wave id: owns n-slice & d-slice [q4*16, q4*16+16)

    const long long batch_stride = (long long)Lc * ROW_STRIDE;
    const float* Qb = Qp + (long long)b * batch_stride + h * Ec;
    const float* Kb = Kp + (long long)b * batch_stride + h * Ec;
    const float* Vb = Vp + (long long)b * batch_stride + h * Ec;
    float*       Ob = Op + (long long)b * batch_stride + h * Ec;

    const int sn = tid >> 2;   // staging: row this thread loads
    const int sc = tid & 3;    // staging: 16-float chunk within row

    // ---- Q row -> 64 VGPRs ----
    float4 qreg[16];
    const float4* qrow =
        reinterpret_cast<const float4*>(Qb + (long long)(qt * BM + m) * ROW_STRIDE);
    #pragma unroll
    for (int i = 0; i < 16; ++i) qreg[i] = qrow[i];

    float mrun = -INFINITY;
    float lrun = 0.f;
    float oacc[16];
    #pragma unroll
    for (int i = 0; i < 16; ++i) oacc[i] = 0.f;

    for (int st = 0; st <= qt; ++st) {
        // ---- stage K/V tile (each thread: 4x float4 of one row chunk) ----
        {
            const float* krow = Kb + (long long)(st * BN + sn) * ROW_STRIDE + sc * 16;
            const float* vrow = Vb + (long long)(st * BN + sn) * ROW_STRIDE + sc * 16;
            const float4* ksrc = reinterpret_cast<const float4*>(krow);
            const float4* vsrc = reinterpret_cast<const float4*>(vrow);
            float4* kdst = reinterpret_cast<float4*>(&kt[sn][sc * 16]);
            float4* vdst = reinterpret_cast<float4*>(&vt[sn][sc * 16]);
            #pragma unroll
            for (int i = 0; i < 4; ++i) { kdst[i] = ksrc[i]; vdst[i] = vsrc[i]; }
        }
        __syncthreads();

        // ---- scores for this wave's n-slice ----
        const bool diag = (st == qt);
        #pragma unroll
        for (int jn = 0; jn < 16; ++jn) {
            const int nn = q4 * 16 + jn;
            float s = 0.f;
            #pragma unroll
            for (int i = 0; i < 16; ++i) {
                const float4 kv = *reinterpret_cast<const float4*>(&kt[nn][i * 4]);
                s = fmaf(qreg[i].x, kv.x, s);
                s = fmaf(qreg[i].y, kv.y, s);
                s = fmaf(qreg[i].z, kv.z, s);
                s = fmaf(qreg[i].w, kv.w, s);
            }
            // fuzzy: (s + delta*sigmoid(s)) * scale, then causal mask
            float f = (s + FUZZ_DELTA / (1.f + __expf(-s))) * SM_SCALE;
            if (diag && nn > m) f = -INFINITY;
            pt[m][nn] = f;
        }
        __syncthreads();

        // ---- online softmax + PV for row m, d-slice q4 ----
        float tmax = -INFINITY;
        #pragma unroll 16
        for (int nn = 0; nn < BN; ++nn) tmax = fmaxf(tmax, pt[m][nn]);
        const float mnew  = fmaxf(mrun, tmax);
        const float alpha = __expf(mrun - mnew);   // first tile: exp(-inf)=0
        mrun = mnew;
        lrun *= alpha;
        #pragma unroll
        for (int i = 0; i < 16; ++i) oacc[i] *= alpha;

        #pragma unroll 4
        for (int nn = 0; nn < BN; ++nn) {
            const float p = __expf(pt[m][nn] - mnew);  // masked: exp(-inf)=0
            lrun += p;
            const float4 v0 = *reinterpret_cast<const float4*>(&vt[nn][q4 * 16 + 0]);
            const float4 v1 = *reinterpret_cast<const float4*>(&vt[nn][q4 * 16 + 4]);
            const float4 v2 = *reinterpret_cast<const float4*>(&vt[nn][q4 * 16 + 8]);
            const float4 v3 = *reinterpret_cast<const float4*>(&vt[nn][q4 * 16 + 12]);
            oacc[0]  = fmaf(p, v0.x, oacc[0]);
            oacc[1]  = fmaf(p, v0.y, oacc[1]);
            oacc[2]  = fmaf(p, v0.z, oacc[2]);
            oacc[3]  = fmaf(p, v0.w, oacc[3]);
            oacc[4]  = fmaf(p, v1.x, oacc[4]);
            oacc[5]  = fmaf(p, v1.y, oacc[5]);
            oacc[6]  = fmaf(p, v1.z, oacc[6]);
            oacc[7]  = fmaf(p, v1.w, oacc[7]);
            oacc[8]  = fmaf(p, v2.x, oacc[8]);
            oacc[9]  = fmaf(p, v2.y, oacc[9]);
            oacc[10] = fmaf(p, v2.z, oacc[10]);
            oacc[11] = fmaf(p, v2.w, oacc[11]);
            oacc[12] = fmaf(p, v3.x, oacc[12]);
            oacc[13] = fmaf(p, v3.y, oacc[13]);
            oacc[14] = fmaf(p, v3.z, oacc[14]);
            oacc[15] = fmaf(p, v3.w, oacc[15]);
        }
        __syncthreads();   // protect kt/vt/pt before next stage
    }

    // ---- epilogue: normalize + write this row's d-slice ----
    const float inv = 1.f / lrun;   // lrun > 0: diagonal always has s=l valid
    float* orow = Ob + (long long)(qt * BM + m) * ROW_STRIDE + q4 * 16;
    float4 o0 = make_float4(oacc[0] * inv,  oacc[1] * inv,  oacc[2] * inv,  oacc[3] * inv);
    float4 o1 = make_float4(oacc[4] * inv,  oacc[5] * inv,  oacc[6] * inv,  oacc[7] * inv);
    float4 o2 = make_float4(oacc[8] * inv,  oacc[9] * inv,  oacc[10] * inv, oacc[11] * inv);
    float4 o3 = make_float4(oacc[12] * inv, oacc[13] * inv, oacc[14] * inv, oacc[15] * inv);
    reinterpret_cast<float4*>(orow)[0] = o0;
    reinterpret_cast<float4*>(orow)[1] = o1;
    reinterpret_cast<float4*>(orow)[2] = o2;
    reinterpret_cast<float4*>(orow)[3] = o3;
}

extern "C" void kernel_launch(void* const* d_in, const int* in_sizes, int n_in,
                              void* d_out, int out_size, void* d_ws, size_t ws_size,
                              hipStream_t stream) {
    (void)in_sizes; (void)n_in; (void)d_ws; (void)ws_size; (void)out_size;
    const float* Q = (const float*)d_in[0];
    const float* K = (const float*)d_in[1];
    const float* V = (const float*)d_in[2];
    // d_in[3] = causal mask (fixed triu k=1) -> handled analytically in-kernel.
    float* O = (float*)d_out;

    dim3 grid(NQT * Bc * Hc);   // 1024 blocks, XCD-swizzled in-kernel
    fuzzy_attn_f32<<<grid, 256, 0, stream>>>(Q, K, V, O);
}

// Round 3
// 96.986 us; speedup vs baseline: 14.5168x; 14.5168x over previous
//
#include <hip/hip_runtime.h>
#include <math.h>

// FuzzyAttention via bf16 MFMA (gfx950 16x16x32).
// V = softmax(0.125*(S + 0.5*sigmoid(S)) causal-masked) @ values, S = Q K^T.
// Q,K,V,out = [B=2, L=2048, H=16, E=64] f32 (converted to bf16 for MFMA inputs).

typedef __bf16 bf16x8 __attribute__((ext_vector_type(8)));
typedef __bf16 bf16x2 __attribute__((ext_vector_type(2)));
typedef float  f32x4  __attribute__((ext_vector_type(4)));

constexpr int Lc = 2048, Hc = 16, Ec = 64;
constexpr int QBLK = 128, KVB = 64;
constexpr int NQT  = Lc / QBLK;        // 16 q-tiles
constexpr int ROWS = Hc * Ec;          // 1024 floats between consecutive l
constexpr float DELTA = 0.5f, SCALE = 0.125f;

// LDS XOR swizzle key for 128B rows: spreads bank usage for both b128 row-chunk
// accesses (lane&15 = row) and the V-transpose b32 writes. 16B-granular.
__device__ __forceinline__ int swz(int row) {
    return ((row & 7) ^ ((row >> 3) & 7)) << 4;
}

__global__ __launch_bounds__(512, 2)
void fuzzy_attn_mfma(const float* __restrict__ Qp, const float* __restrict__ Kp,
                     const float* __restrict__ Vp, float* __restrict__ Op) {
    __shared__ __bf16 kt[KVB * Ec];      // [kv][e]   row-major, swizzled (8 KB)
    __shared__ __bf16 vt[Ec * KVB];      // [d][kv]   transposed,  swizzled (8 KB)
    __shared__ __bf16 pt[8][16 * KVB];   // per-wave P [q16][kv], swizzled (16 KB)
    __shared__ float  red[8][16];        // per-wave alpha / 1/l broadcast

    // ---- block decode: all 8 q-pair-blocks of one (b,h) on one XCD ----
    const int id    = blockIdx.x;        // 0..255
    const int xcd   = id & 7;
    const int inner = id >> 3;           // 0..31
    const int bh    = xcd + 8 * (inner & 3);   // 0..31
    const int pairi = inner >> 2;        // 0..7
    const int b = bh >> 4, h = bh & 15;

    const int tid  = threadIdx.x;
    const int lane = tid & 63;
    const int w    = tid >> 6;           // wave 0..7, owns q rows w*16..+16
    const int q16  = lane & 15;
    const int g    = lane >> 4;          // 0..3 (k-group)

    const size_t bstride = (size_t)Lc * ROWS;
    const float* Qb = Qp + (size_t)b * bstride + h * Ec;
    const float* Kb = Kp + (size_t)b * bstride + h * Ec;
    const float* Vb = Vp + (size_t)b * bstride + h * Ec;
    float*       Ob = Op + (size_t)b * bstride + h * Ec;

    // paired q-tiles: (x, 15-x) -> (2x+2)+(2(15-x)+2) = 34 KV-iters, balanced
    const int qts[2] = { pairi, NQT - 1 - pairi };

    for (int qi = 0; qi < 2; ++qi) {
        const int qt   = qts[qi];
        const int qrow = qt * QBLK + w * 16 + q16;   // lane's q row (B-frag col)

        // ---- Q B-frags: lane holds Q[qrow][g*8 + 32*ks .. +8] as bf16 ----
        bf16x8 qb[2];
        #pragma unroll
        for (int ks = 0; ks < 2; ++ks) {
            const float* qp = Qb + (size_t)qrow * ROWS + g * 8 + 32 * ks;
            float4 x0 = reinterpret_cast<const float4*>(qp)[0];
            float4 x1 = reinterpret_cast<const float4*>(qp)[1];
            bf16x8 t;
            t[0] = (__bf16)x0.x; t[1] = (__bf16)x0.y; t[2] = (__bf16)x0.z; t[3] = (__bf16)x0.w;
            t[4] = (__bf16)x1.x; t[5] = (__bf16)x1.y; t[6] = (__bf16)x1.z; t[7] = (__bf16)x1.w;
            qb[ks] = t;
        }

        float mrun = -INFINITY, lrun = 0.f;
        f32x4 oacc[4];
        #pragma unroll
        for (int dt = 0; dt < 4; ++dt) {
            f32x4 z = {0.f, 0.f, 0.f, 0.f};
            oacc[dt] = z;
        }

        const int nst = 2 * qt + 2;
        for (int st = 0; st < nst; ++st) {
            __syncthreads();   // prev-iter LDS reads complete before overwrite

            // ---- stage: waves 0-3 convert K rows, waves 4-7 transpose V ----
            if (tid < 256) {
                #pragma unroll
                for (int sI = 0; sI < 2; ++sI) {
                    int s = tid + sI * 256;        // 512 slots: (row, 8-elem chunk)
                    int row = s >> 3, ch = s & 7;
                    const float4* src = reinterpret_cast<const float4*>(
                        Kb + (size_t)(st * KVB + row) * ROWS + ch * 8);
                    float4 a = src[0], c = src[1];
                    bf16x8 t;
                    t[0] = (__bf16)a.x; t[1] = (__bf16)a.y; t[2] = (__bf16)a.z; t[3] = (__bf16)a.w;
                    t[4] = (__bf16)c.x; t[5] = (__bf16)c.y; t[6] = (__bf16)c.z; t[7] = (__bf16)c.w;
                    *reinterpret_cast<bf16x8*>(
                        reinterpret_cast<char*>(kt) + row * 128 + ((ch * 16) ^ swz(row))) = t;
                }
            } else {
                int s = tid - 256;                 // 256 slots: (kv-pair, 8-d chunk)
                int kvp = s >> 3, ch = s & 7;
                const float* r0 = Vb + (size_t)(st * KVB + 2 * kvp) * ROWS + ch * 8;
                const float* r1 = r0 + ROWS;
                float4 a0 = reinterpret_cast<const float4*>(r0)[0];
                float4 a1 = reinterpret_cast<const float4*>(r0)[1];
                float4 c0 = reinterpret_cast<const float4*>(r1)[0];
                float4 c1 = reinterpret_cast<const float4*>(r1)[1];
                float lo[8] = {a0.x, a0.y, a0.z, a0.w, a1.x, a1.y, a1.z, a1.w};
                float hi[8] = {c0.x, c0.y, c0.z, c0.w, c1.x, c1.y, c1.z, c1.w};
                #pragma unroll
                for (int i = 0; i < 8; ++i) {      // vt[d][kv pair] b32 writes
                    int d = ch * 8 + i;
                    bf16x2 p; p[0] = (__bf16)lo[i]; p[1] = (__bf16)hi[i];
                    *reinterpret_cast<bf16x2*>(
                        reinterpret_cast<char*>(vt) + d * 128 + ((4 * kvp) ^ swz(d))) = p;
                }
            }
            __syncthreads();

            // ---- QK^T (swapped): S^T[kv][q] tiles, 4 kv-subtiles x 2 k-slices ----
            f32x4 sacc[4];
            #pragma unroll
            for (int tt = 0; tt < 4; ++tt) {
                f32x4 z = {0.f, 0.f, 0.f, 0.f};
                sacc[tt] = z;
            }
            #pragma unroll
            for (int tt = 0; tt < 4; ++tt) {
                int kvr = tt * 16 + q16;           // A-frag row = kv
                #pragma unroll
                for (int ks = 0; ks < 2; ++ks) {
                    bf16x8 ka = *reinterpret_cast<const bf16x8*>(
                        reinterpret_cast<const char*>(kt) + kvr * 128 +
                        ((g * 16 + 64 * ks) ^ swz(kvr)));
                    sacc[tt] = __builtin_amdgcn_mfma_f32_16x16x32_bf16(ka, qb[ks], sacc[tt], 0, 0, 0);
                }
            }

            // ---- fuzzy + causal mask + online softmax (row = q16, lane-group) ----
            // D layout: col=lane&15 -> q16; row=(lane>>4)*4+reg -> kv-in-subtile.
            const bool diagband = (st * KVB + KVB - 1 > qt * QBLK + w * 16);
            float fv[16];
            float tmax = -INFINITY;
            #pragma unroll
            for (int tt = 0; tt < 4; ++tt) {
                #pragma unroll
                for (int r = 0; r < 4; ++r) {
                    float s = sacc[tt][r];
                    float f = (s + DELTA / (1.f + __expf(-s))) * SCALE;
                    if (diagband) {
                        int kvg = st * KVB + tt * 16 + g * 4 + r;
                        if (kvg > qrow) f = -INFINITY;
                    }
                    fv[tt * 4 + r] = f;
                    tmax = fmaxf(tmax, f);
                }
            }
            tmax = fmaxf(tmax, __shfl_xor(tmax, 16));
            tmax = fmaxf(tmax, __shfl_xor(tmax, 32));
            const float mnew  = fmaxf(mrun, tmax);
            const float alpha = __expf(mrun - mnew);   // first tile: exp(-inf)=0
            mrun = mnew;

            // p = exp(f - mnew); write P (bf16) to per-wave LDS; partial row sum
            char* pw = reinterpret_cast<char*>(pt[w]);
            float psum = 0.f;
            #pragma unroll
            for (int tt = 0; tt < 4; ++tt) {
                #pragma unroll
                for (int hh = 0; hh < 2; ++hh) {
                    float p0 = __expf(fv[tt * 4 + 2 * hh]     - mnew);
                    float p1 = __expf(fv[tt * 4 + 2 * hh + 1] - mnew);
                    psum += p0 + p1;
                    bf16x2 p2; p2[0] = (__bf16)p0; p2[1] = (__bf16)p1;
                    // kv = g*4 + {2hh,2hh+1} + 16*tt  ->  colByte = 8g + 4hh + 32tt
                    *reinterpret_cast<bf16x2*>(
                        pw + q16 * 128 + ((8 * g + 4 * hh + 32 * tt) ^ swz(q16))) = p2;
                }
            }
            psum += __shfl_xor(psum, 16);
            psum += __shfl_xor(psum, 32);
            lrun = lrun * alpha + psum;

            // broadcast alpha by q-row (O-acc lanes own different q than softmax lanes)
            if (lane < 16) red[w][lane] = alpha;   // within-wave LDS, no barrier needed
            float a4[4];
            #pragma unroll
            for (int r = 0; r < 4; ++r) a4[r] = red[w][g * 4 + r];
            #pragma unroll
            for (int dt = 0; dt < 4; ++dt) {
                #pragma unroll
                for (int r = 0; r < 4; ++r) oacc[dt][r] *= a4[r];
            }

            // ---- PV: O[q][d] += P[q][kv] V[kv][d] ----
            #pragma unroll
            for (int ks = 0; ks < 2; ++ks) {
                bf16x8 pa = *reinterpret_cast<const bf16x8*>(
                    pw + q16 * 128 + ((g * 16 + 64 * ks) ^ swz(q16)));
                #pragma unroll
                for (int dt = 0; dt < 4; ++dt) {
                    int d = dt * 16 + q16;         // vt row (transposed layout)
                    bf16x8 vb = *reinterpret_cast<const bf16x8*>(
                        reinterpret_cast<const char*>(vt) + d * 128 +
                        ((g * 16 + 64 * ks) ^ swz(d)));
                    oacc[dt] = __builtin_amdgcn_mfma_f32_16x16x32_bf16(pa, vb, oacc[dt], 0, 0, 0);
                }
            }
        }

        // ---- epilogue: normalize, write O (lane owns q = g*4+r, d = dt*16+q16) ----
        if (lane < 16) red[w][lane] = 1.f / lrun;
        float i4[4];
        #pragma unroll
        for (int r = 0; r < 4; ++r) i4[r] = red[w][g * 4 + r];
        #pragma unroll
        for (int dt = 0; dt < 4; ++dt) {
            #pragma unroll
            for (int r = 0; r < 4; ++r) {
                int row = qt * QBLK + w * 16 + g * 4 + r;
                Ob[(size_t)row * ROWS + dt * 16 + q16] = oacc[dt][r] * i4[r];
            }
        }
    }
}

extern "C" void kernel_launch(void* const* d_in, const int* in_sizes, int n_in,
                              void* d_out, int out_size, void* d_ws, size_t ws_size,
                              hipStream_t stream) {
    (void)in_sizes; (void)n_in; (void)d_ws; (void)ws_size; (void)out_size;
    const float* Q = (const float*)d_in[0];
    const float* K = (const float*)d_in[1];
    const float* V = (const float*)d_in[2];
    // d_in[3] = causal mask (fixed triu k=1) -> handled analytically in-kernel.
    float* O = (float*)d_out;

    fuzzy_attn_mfma<<<dim3(256), dim3(512), 0, stream>>>(Q, K, V, O);
}

// Round 4
// 94.726 us; speedup vs baseline: 14.8632x; 1.0239x over previous
//
#include <hip/hip_runtime.h>
#include <math.h>

// FuzzyAttention via bf16 MFMA (gfx950 16x16x32).
// V = softmax(0.125*(S + 0.5*sigmoid(S)) causal-masked) @ values, S = Q K^T.
// Q,K,V,out = [B=2, L=2048, H=16, E=64] f32 (converted to bf16 for MFMA inputs).

typedef __bf16 bf16x8 __attribute__((ext_vector_type(8)));
typedef __bf16 bf16x2 __attribute__((ext_vector_type(2)));
typedef float  f32x4  __attribute__((ext_vector_type(4)));

constexpr int Lc = 2048, Hc = 16, Ec = 64;
constexpr int QBLK = 128, KVB = 64;
constexpr int NQT  = Lc / QBLK;        // 16 q-tiles
constexpr int ROWS = Hc * Ec;          // 1024 floats between consecutive l
constexpr float DELTA = 0.5f, SCALE = 0.125f;

// LDS XOR swizzle key for 128B rows (16B granular).
__device__ __forceinline__ int swz(int row) {
    return ((row & 7) ^ ((row >> 3) & 7)) << 4;
}

__global__ __launch_bounds__(512, 2)
void fuzzy_attn_mfma(const float* __restrict__ Qp, const float* __restrict__ Kp,
                     const float* __restrict__ Vp, float* __restrict__ Op) {
    __shared__ __bf16 kt[KVB * Ec];      // [kv][e]   row-major, swizzled (8 KB)
    __shared__ __bf16 vt[Ec * KVB];      // [d][kv]   transposed,  swizzled (8 KB)
    __shared__ __bf16 pt[8][16 * KVB];   // per-wave P [q16][kv], swizzled (16 KB)

    // ---- block decode ----
    // Dispatch model (measured: id%8 = XCD): within an XCD, j=id>>3 fills CU
    // slots in order; j and j+32 share a CU. Map them to complementary q-tiles
    // (qt, 15-qt) of the SAME head -> each CU ~34 iters, one head's K/V in L2.
    const int id  = blockIdx.x;          // 0..511
    const int xcd = id & 7;
    const int j   = id >> 3;             // 0..63
    const int s4  = j & 3;
    const int t   = j >> 2;              // 0..15
    const int bh  = s4 * 8 + xcd;        // 4 heads per XCD
    const int qt  = (t < 8) ? (NQT - 1 - t) : (t - 8);
    const int b = bh >> 4, h = bh & 15;

    const int tid  = threadIdx.x;
    const int lane = tid & 63;
    const int w    = tid >> 6;           // wave 0..7, owns q rows w*16..+16
    const int q16  = lane & 15;
    const int g    = lane >> 4;          // 0..3 (k-group)

    const size_t bstride = (size_t)Lc * ROWS;
    const float* Qb = Qp + (size_t)b * bstride + h * Ec;
    const float* Kb = Kp + (size_t)b * bstride + h * Ec;
    const float* Vb = Vp + (size_t)b * bstride + h * Ec;
    float*       Ob = Op + (size_t)b * bstride + h * Ec;

    const int qrow = qt * QBLK + w * 16 + q16;   // lane's q row (B-frag col)

    // ---- Q B-frags: lane holds Q[qrow][g*8 + 32*ks .. +8] as bf16 ----
    bf16x8 qb[2];
    #pragma unroll
    for (int ks = 0; ks < 2; ++ks) {
        const float* qp = Qb + (size_t)qrow * ROWS + g * 8 + 32 * ks;
        float4 x0 = reinterpret_cast<const float4*>(qp)[0];
        float4 x1 = reinterpret_cast<const float4*>(qp)[1];
        bf16x8 tq;
        tq[0] = (__bf16)x0.x; tq[1] = (__bf16)x0.y; tq[2] = (__bf16)x0.z; tq[3] = (__bf16)x0.w;
        tq[4] = (__bf16)x1.x; tq[5] = (__bf16)x1.y; tq[6] = (__bf16)x1.z; tq[7] = (__bf16)x1.w;
        qb[ks] = tq;
    }

    float mrun = -INFINITY, lrun = 0.f;
    f32x4 oacc[4];
    #pragma unroll
    for (int dt = 0; dt < 4; ++dt) {
        f32x4 z = {0.f, 0.f, 0.f, 0.f};
        oacc[dt] = z;
    }

    const int nst = 2 * qt + 2;
    for (int st = 0; st < nst; ++st) {
        __syncthreads();   // prev-iter LDS reads complete before overwrite

        // ---- stage: waves 0-3 convert K rows, waves 4-7 transpose V ----
        if (tid < 256) {
            #pragma unroll
            for (int sI = 0; sI < 2; ++sI) {
                int s = tid + sI * 256;        // 512 slots: (row, 8-elem chunk)
                int row = s >> 3, ch = s & 7;
                const float4* src = reinterpret_cast<const float4*>(
                    Kb + (size_t)(st * KVB + row) * ROWS + ch * 8);
                float4 a = src[0], c = src[1];
                bf16x8 tk;
                tk[0] = (__bf16)a.x; tk[1] = (__bf16)a.y; tk[2] = (__bf16)a.z; tk[3] = (__bf16)a.w;
                tk[4] = (__bf16)c.x; tk[5] = (__bf16)c.y; tk[6] = (__bf16)c.z; tk[7] = (__bf16)c.w;
                *reinterpret_cast<bf16x8*>(
                    reinterpret_cast<char*>(kt) + row * 128 + ((ch * 16) ^ swz(row))) = tk;
            }
        } else {
            int s = tid - 256;                 // 256 slots: (kv-pair, 8-d chunk)
            int kvp = s >> 3, ch = s & 7;
            const float* r0 = Vb + (size_t)(st * KVB + 2 * kvp) * ROWS + ch * 8;
            const float* r1 = r0 + ROWS;
            float4 a0 = reinterpret_cast<const float4*>(r0)[0];
            float4 a1 = reinterpret_cast<const float4*>(r0)[1];
            float4 c0 = reinterpret_cast<const float4*>(r1)[0];
            float4 c1 = reinterpret_cast<const float4*>(r1)[1];
            float lo[8] = {a0.x, a0.y, a0.z, a0.w, a1.x, a1.y, a1.z, a1.w};
            float hi[8] = {c0.x, c0.y, c0.z, c0.w, c1.x, c1.y, c1.z, c1.w};
            #pragma unroll
            for (int i = 0; i < 8; ++i) {      // vt[d][kv pair] b32 writes
                int d = ch * 8 + i;
                bf16x2 p; p[0] = (__bf16)lo[i]; p[1] = (__bf16)hi[i];
                *reinterpret_cast<bf16x2*>(
                    reinterpret_cast<char*>(vt) + d * 128 + ((4 * kvp) ^ swz(d))) = p;
            }
        }
        __syncthreads();

        // ---- QK^T (swapped): S^T[kv][q] tiles, 4 kv-subtiles x 2 k-slices ----
        f32x4 sacc[4];
        #pragma unroll
        for (int tt = 0; tt < 4; ++tt) {
            f32x4 z = {0.f, 0.f, 0.f, 0.f};
            sacc[tt] = z;
        }
        #pragma unroll
        for (int tt = 0; tt < 4; ++tt) {
            int kvr = tt * 16 + q16;           // A-frag row = kv
            #pragma unroll
            for (int ks = 0; ks < 2; ++ks) {
                bf16x8 ka = *reinterpret_cast<const bf16x8*>(
                    reinterpret_cast<const char*>(kt) + kvr * 128 +
                    ((g * 16 + 64 * ks) ^ swz(kvr)));
                sacc[tt] = __builtin_amdgcn_mfma_f32_16x16x32_bf16(ka, qb[ks], sacc[tt], 0, 0, 0);
            }
        }

        // ---- fuzzy + causal mask + online softmax (row = q16, lane-group) ----
        // D layout: col=lane&15 -> q16; row=(lane>>4)*4+reg -> kv-in-subtile.
        const bool diagband = (st * KVB + KVB - 1 > qt * QBLK + w * 16);
        float fv[16];
        float tmax = -INFINITY;
        #pragma unroll
        for (int tt = 0; tt < 4; ++tt) {
            #pragma unroll
            for (int r = 0; r < 4; ++r) {
                float s = sacc[tt][r];
                float f = (s + DELTA / (1.f + __expf(-s))) * SCALE;
                if (diagband) {
                    int kvg = st * KVB + tt * 16 + g * 4 + r;
                    if (kvg > qrow) f = -INFINITY;
                }
                fv[tt * 4 + r] = f;
                tmax = fmaxf(tmax, f);
            }
        }
        tmax = fmaxf(tmax, __shfl_xor(tmax, 16));
        tmax = fmaxf(tmax, __shfl_xor(tmax, 32));
        const float mnew  = fmaxf(mrun, tmax);
        const float alpha = __expf(mrun - mnew);   // first tile: exp(-inf)=0
        mrun = mnew;

        // p = exp(f - mnew); write P (bf16) to per-wave LDS; partial row sum
        char* pw = reinterpret_cast<char*>(pt[w]);
        float psum = 0.f;
        #pragma unroll
        for (int tt = 0; tt < 4; ++tt) {
            #pragma unroll
            for (int hh = 0; hh < 2; ++hh) {
                float p0 = __expf(fv[tt * 4 + 2 * hh]     - mnew);
                float p1 = __expf(fv[tt * 4 + 2 * hh + 1] - mnew);
                psum += p0 + p1;
                bf16x2 p2; p2[0] = (__bf16)p0; p2[1] = (__bf16)p1;
                // kv = g*4 + {2hh,2hh+1} + 16*tt  ->  colByte = 8g + 4hh + 32tt
                *reinterpret_cast<bf16x2*>(
                    pw + q16 * 128 + ((8 * g + 4 * hh + 32 * tt) ^ swz(q16))) = p2;
            }
        }
        psum += __shfl_xor(psum, 16);
        psum += __shfl_xor(psum, 32);
        lrun = lrun * alpha + psum;

        // broadcast alpha by q-row via shfl (lane g*4+r computed row g*4+r's alpha)
        float a4[4];
        #pragma unroll
        for (int r = 0; r < 4; ++r) a4[r] = __shfl(alpha, g * 4 + r);
        #pragma unroll
        for (int dt = 0; dt < 4; ++dt) {
            #pragma unroll
            for (int r = 0; r < 4; ++r) oacc[dt][r] *= a4[r];
        }

        // ---- PV: O[q][d] += P[q][kv] V[kv][d] ----
        #pragma unroll
        for (int ks = 0; ks < 2; ++ks) {
            bf16x8 pa = *reinterpret_cast<const bf16x8*>(
                pw + q16 * 128 + ((g * 16 + 64 * ks) ^ swz(q16)));
            #pragma unroll
            for (int dt = 0; dt < 4; ++dt) {
                int d = dt * 16 + q16;         // vt row (transposed layout)
                bf16x8 vb = *reinterpret_cast<const bf16x8*>(
                    reinterpret_cast<const char*>(vt) + d * 128 +
                    ((g * 16 + 64 * ks) ^ swz(d)));
                oacc[dt] = __builtin_amdgcn_mfma_f32_16x16x32_bf16(pa, vb, oacc[dt], 0, 0, 0);
            }
        }
    }

    // ---- epilogue: normalize, write O (lane owns q = g*4+r, d = dt*16+q16) ----
    const float inv = 1.f / lrun;
    float i4[4];
    #pragma unroll
    for (int r = 0; r < 4; ++r) i4[r] = __shfl(inv, g * 4 + r);
    #pragma unroll
    for (int dt = 0; dt < 4; ++dt) {
        #pragma unroll
        for (int r = 0; r < 4; ++r) {
            int row = qt * QBLK + w * 16 + g * 4 + r;
            Ob[(size_t)row * ROWS + dt * 16 + q16] = oacc[dt][r] * i4[r];
        }
    }
}

extern "C" void kernel_launch(void* const* d_in, const int* in_sizes, int n_in,
                              void* d_out, int out_size, void* d_ws, size_t ws_size,
                              hipStream_t stream) {
    (void)in_sizes; (void)n_in; (void)d_ws; (void)ws_size; (void)out_size;
    const float* Q = (const float*)d_in[0];
    const float* K = (const float*)d_in[1];
    const float* V = (const float*)d_in[2];
    // d_in[3] = causal mask (fixed triu k=1) -> handled analytically in-kernel.
    float* O = (float*)d_out;

    fuzzy_attn_mfma<<<dim3(512), dim3(512), 0, stream>>>(Q, K, V, O);
}

// Round 5
// 81.005 us; speedup vs baseline: 17.3807x; 1.1694x over previous
//
#include <hip/hip_runtime.h>
#include <math.h>

// FuzzyAttention via bf16 MFMA (gfx950 16x16x32), global_load_lds staging.
// V = softmax(0.125*(S + 0.5*sigmoid(S)) causal-masked) @ values, S = Q K^T.
// Q,K,V,out = [B=2, L=2048, H=16, E=64] f32.
// Pre-pass: K -> bf16 [bh][l][e], V -> bf16 transposed [bh][d][l] in d_ws.

typedef __bf16 bf16x8 __attribute__((ext_vector_type(8)));
typedef __bf16 bf16x4 __attribute__((ext_vector_type(4)));
typedef float  f32x4  __attribute__((ext_vector_type(4)));

constexpr int Lc = 2048, Hc = 16, Ec = 64;
constexpr int QBLK = 128, KVB = 64;
constexpr int NQT  = Lc / QBLK;        // 16 q-tiles
constexpr int ROWS = Hc * Ec;          // 1024 floats between consecutive l
constexpr float LOG2E = 1.4426950408889634f;
constexpr float C1 = 0.125f * LOG2E;          // s coeff   (base-2 softmax)
constexpr float C2 = 0.5f * 0.125f * LOG2E;   // sigmoid coeff
constexpr float RTHR = 12.f;                  // defer-rescale threshold (log2)

// ---------------- pre-pass: K f32 [b][l][h][e] -> bf16 [bh][l][e] ----------------
__global__ __launch_bounds__(256)
void conv_k(const float* __restrict__ Kp, __bf16* __restrict__ Kbf) {
    const int task = blockIdx.x * 256 + threadIdx.x;   // 262144 tasks
    const int row = task >> 2, q4 = task & 3;          // row = (b*2048+l)*16+h
    const int h = row & 15, bl = row >> 4;
    const int b = bl >> 11, l = bl & 2047;
    const float4* src = reinterpret_cast<const float4*>(Kp + (size_t)row * 64 + q4 * 16);
    __bf16* dst = Kbf + ((size_t)((b * 16 + h) * 2048 + l)) * 64 + q4 * 16;
    float4 x0 = src[0], x1 = src[1], x2 = src[2], x3 = src[3];
    bf16x8 o0, o1;
    o0[0]=(__bf16)x0.x; o0[1]=(__bf16)x0.y; o0[2]=(__bf16)x0.z; o0[3]=(__bf16)x0.w;
    o0[4]=(__bf16)x1.x; o0[5]=(__bf16)x1.y; o0[6]=(__bf16)x1.z; o0[7]=(__bf16)x1.w;
    o1[0]=(__bf16)x2.x; o1[1]=(__bf16)x2.y; o1[2]=(__bf16)x2.z; o1[3]=(__bf16)x2.w;
    o1[4]=(__bf16)x3.x; o1[5]=(__bf16)x3.y; o1[6]=(__bf16)x3.z; o1[7]=(__bf16)x3.w;
    reinterpret_cast<bf16x8*>(dst)[0] = o0;
    reinterpret_cast<bf16x8*>(dst)[1] = o1;
}

// ------------- pre-pass: V f32 [b][l][h][d] -> bf16 transposed [bh][d][l] -------------
__global__ __launch_bounds__(256)
void conv_v(const float* __restrict__ Vp, __bf16* __restrict__ Vbf) {
    __shared__ __bf16 tl[64 * 72];     // [d][l], pitch 72 bf16 = 144 B (16B-aligned rows)
    const int bh = blockIdx.y, lt = blockIdx.x;
    const int b = bh >> 4, h = bh & 15;
    const int tid = threadIdx.x;
    {   // load 64 l-rows x 64 d, convert, write transposed into LDS
        const int l = tid >> 2, dc = tid & 3;
        const float4* src = reinterpret_cast<const float4*>(
            Vp + ((size_t)((b * 2048 + lt * 64 + l) * 16 + h)) * 64 + dc * 16);
        float4 v0 = src[0], v1 = src[1], v2 = src[2], v3 = src[3];
        float e[16] = {v0.x,v0.y,v0.z,v0.w, v1.x,v1.y,v1.z,v1.w,
                       v2.x,v2.y,v2.z,v2.w, v3.x,v3.y,v3.z,v3.w};
        #pragma unroll
        for (int i = 0; i < 16; ++i) tl[(dc * 16 + i) * 72 + l] = (__bf16)e[i];
    }
    __syncthreads();
    {   // store rows of V^T coalesced
        const int d = tid >> 2, lc = tid & 3;
        bf16x8 a = *reinterpret_cast<const bf16x8*>(&tl[d * 72 + lc * 16]);
        bf16x8 c = *reinterpret_cast<const bf16x8*>(&tl[d * 72 + lc * 16 + 8]);
        __bf16* dst = Vbf + ((size_t)bh * 64 + d) * 2048 + lt * 64 + lc * 16;
        reinterpret_cast<bf16x8*>(dst)[0] = a;
        reinterpret_cast<bf16x8*>(dst)[1] = c;
    }
}

// ---------------------------------- main kernel ----------------------------------
__global__ __launch_bounds__(512, 4)
void fuzzy_attn_mfma(const float* __restrict__ Qp, const __bf16* __restrict__ Kbf,
                     const __bf16* __restrict__ Vbf, float* __restrict__ Op) {
    __shared__ __bf16 kt[2][KVB * Ec];   // K tile, double-buffered, linear+src-swizzled
    __shared__ __bf16 vt[2][KVB * Ec];   // V^T tile, double-buffered
    __shared__ __bf16 pt[8][16 * KVB];   // per-wave P [q16][kv]

    // block decode: id%8 = XCD; j and j+32 share a CU -> complementary q-tiles, same head
    const int id  = blockIdx.x;          // 0..511
    const int xcd = id & 7;
    const int j   = id >> 3;
    const int s4  = j & 3;
    const int t   = j >> 2;
    const int bh  = s4 * 8 + xcd;
    const int qt  = (t < 8) ? (NQT - 1 - t) : (t - 8);
    const int b = bh >> 4, h = bh & 15;

    const int tid  = threadIdx.x;
    const int lane = tid & 63;
    const int w    = tid >> 6;           // wave 0..7, owns q rows w*16..+16
    const int q16  = lane & 15;
    const int g    = lane >> 4;          // 0..3 (k-group)

    const __bf16* Kh = Kbf + (size_t)bh * (Lc * Ec);
    const __bf16* Vh = Vbf + (size_t)bh * (Ec * Lc);
    const float*  Qb = Qp + (size_t)b * Lc * ROWS + h * Ec;
    float*        Ob = Op + (size_t)b * Lc * ROWS + h * Ec;

    const int qrow = qt * QBLK + w * 16 + q16;

    // staging: wave w fills rows 8w..8w+7; lane -> (row, chunk), source chunk
    // pre-XORed so the LINEAR LDS write lands swizzled (read side XORs the same key).
    const int srow = w * 8 + (lane >> 3);
    const int skey = (srow & 7) ^ (srow >> 3);
    const int sch  = (lane & 7) ^ skey;
    const __bf16* kg0 = Kh + srow * 64   + sch * 8;   // + st*4096 per tile
    const __bf16* vg0 = Vh + srow * 2048 + sch * 8;   // + st*64   per tile

    // ---- Q B-frags: lane holds Q[qrow][g*8 + 32*ks .. +8] as bf16 ----
    bf16x8 qb[2];
    #pragma unroll
    for (int ks = 0; ks < 2; ++ks) {
        const float* qp = Qb + (size_t)qrow * ROWS + g * 8 + 32 * ks;
        float4 x0 = reinterpret_cast<const float4*>(qp)[0];
        float4 x1 = reinterpret_cast<const float4*>(qp)[1];
        bf16x8 tq;
        tq[0]=(__bf16)x0.x; tq[1]=(__bf16)x0.y; tq[2]=(__bf16)x0.z; tq[3]=(__bf16)x0.w;
        tq[4]=(__bf16)x1.x; tq[5]=(__bf16)x1.y; tq[6]=(__bf16)x1.z; tq[7]=(__bf16)x1.w;
        qb[ks] = tq;
    }

    const int nst = 2 * qt + 2;

    // prefetch tile 0 into buf 0
    __builtin_amdgcn_global_load_lds((const __attribute__((address_space(1))) void*)kg0,
        (__attribute__((address_space(3))) void*)&kt[0][w * 512], 16, 0, 0);
    __builtin_amdgcn_global_load_lds((const __attribute__((address_space(1))) void*)vg0,
        (__attribute__((address_space(3))) void*)&vt[0][w * 512], 16, 0, 0);

    float mrun = -INFINITY, lrun = 0.f;
    f32x4 oacc[4];
    #pragma unroll
    for (int dt = 0; dt < 4; ++dt) { f32x4 z = {0.f,0.f,0.f,0.f}; oacc[dt] = z; }

    const int pkey = ((q16 & 7) ^ (q16 >> 3)) << 4;
    char* pw = reinterpret_cast<char*>(pt[w]);

    for (int st = 0; st < nst; ++st) {
        const int buf = st & 1;
        __syncthreads();   // vmcnt(0)+barrier: tile[buf] landed; prev reads done

        if (st + 1 < nst) {   // prefetch next tile into buf^1 (lands by next barrier)
            const __bf16* kg = kg0 + (size_t)(st + 1) * (KVB * Ec);
            const __bf16* vg = vg0 + (st + 1) * KVB;
            __builtin_amdgcn_global_load_lds((const __attribute__((address_space(1))) void*)kg,
                (__attribute__((address_space(3))) void*)&kt[buf ^ 1][w * 512], 16, 0, 0);
            __builtin_amdgcn_global_load_lds((const __attribute__((address_space(1))) void*)vg,
                (__attribute__((address_space(3))) void*)&vt[buf ^ 1][w * 512], 16, 0, 0);
        }

        const char* kbase = reinterpret_cast<const char*>(kt[buf]);
        const char* vbase = reinterpret_cast<const char*>(vt[buf]);

        // ---- QK^T (swapped): S^T[kv][q] ----
        f32x4 sacc[4];
        #pragma unroll
        for (int tt = 0; tt < 4; ++tt) { f32x4 z = {0.f,0.f,0.f,0.f}; sacc[tt] = z; }
        #pragma unroll
        for (int tt = 0; tt < 4; ++tt) {
            const int kvr  = tt * 16 + q16;
            const int kkey = ((kvr & 7) ^ (kvr >> 3)) << 4;
            #pragma unroll
            for (int ks = 0; ks < 2; ++ks) {
                bf16x8 ka = *reinterpret_cast<const bf16x8*>(
                    kbase + kvr * 128 + (((g + 4 * ks) << 4) ^ kkey));
                sacc[tt] = __builtin_amdgcn_mfma_f32_16x16x32_bf16(ka, qb[ks], sacc[tt], 0, 0, 0);
            }
        }

        // ---- fuzzy (base-2) + causal mask; D: col=q16 -> q, row=g*4+r -> kv ----
        const bool diagband = (st * KVB + KVB - 1 > qt * QBLK + w * 16);
        float fv[16];
        float tmax = -INFINITY;
        #pragma unroll
        for (int tt = 0; tt < 4; ++tt) {
            #pragma unroll
            for (int r = 0; r < 4; ++r) {
                const float s  = sacc[tt][r];
                const float en = __builtin_amdgcn_exp2f(s * -LOG2E);
                const float sg = __builtin_amdgcn_rcpf(1.f + en);
                float f2 = fmaf(s, C1, sg * C2);   // log2-units fuzzy score
                if (diagband) {
                    const int kvg = st * KVB + tt * 16 + g * 4 + r;
                    if (kvg > qrow) f2 = -INFINITY;
                }
                fv[tt * 4 + r] = f2;
                tmax = fmaxf(tmax, f2);
            }
        }
        tmax = fmaxf(tmax, __shfl_xor(tmax, 16));
        tmax = fmaxf(tmax, __shfl_xor(tmax, 32));

        // defer-max: rescale only when the tile max grew past THR (rare)
        float m2 = mrun;
        if (!__all(tmax - mrun <= RTHR)) {
            const float mnew  = fmaxf(mrun, tmax);
            const float alpha = __builtin_amdgcn_exp2f(mrun - mnew); // 1st iter: 0
            float a4[4];
            #pragma unroll
            for (int r = 0; r < 4; ++r) a4[r] = __shfl(alpha, g * 4 + r);
            #pragma unroll
            for (int dt = 0; dt < 4; ++dt) {
                #pragma unroll
                for (int r = 0; r < 4; ++r) oacc[dt][r] *= a4[r];
            }
            lrun *= alpha;
            mrun = mnew;
            m2   = mnew;
        }

        // ---- p = exp2(f2 - m2); pack bf16x4, write P; row-sum ----
        float psum = 0.f;
        #pragma unroll
        for (int tt = 0; tt < 4; ++tt) {
            const float p0 = __builtin_amdgcn_exp2f(fv[tt * 4 + 0] - m2);
            const float p1 = __builtin_amdgcn_exp2f(fv[tt * 4 + 1] - m2);
            const float p2 = __builtin_amdgcn_exp2f(fv[tt * 4 + 2] - m2);
            const float p3 = __builtin_amdgcn_exp2f(fv[tt * 4 + 3] - m2);
            psum += (p0 + p1) + (p2 + p3);
            bf16x4 pk;
            pk[0]=(__bf16)p0; pk[1]=(__bf16)p1; pk[2]=(__bf16)p2; pk[3]=(__bf16)p3;
            *reinterpret_cast<bf16x4*>(pw + q16 * 128 + ((8 * g + 32 * tt) ^ pkey)) = pk;
        }
        psum += __shfl_xor(psum, 16);
        psum += __shfl_xor(psum, 32);
        lrun += psum;

        // ---- PV: O[q][d] += P[q][kv] V[kv][d] ----
        #pragma unroll
        for (int ks = 0; ks < 2; ++ks) {
            bf16x8 pa = *reinterpret_cast<const bf16x8*>(
                pw + q16 * 128 + (((g + 4 * ks) << 4) ^ pkey));
            #pragma unroll
            for (int dt = 0; dt < 4; ++dt) {
                const int d    = dt * 16 + q16;
                const int vkey = ((d & 7) ^ (d >> 3)) << 4;
                bf16x8 vb = *reinterpret_cast<const bf16x8*>(
                    vbase + d * 128 + (((g + 4 * ks) << 4) ^ vkey));
                oacc[dt] = __builtin_amdgcn_mfma_f32_16x16x32_bf16(pa, vb, oacc[dt], 0, 0, 0);
            }
        }
    }

    // ---- epilogue: normalize, write O (lane owns q = g*4+r, d = dt*16+q16) ----
    const float inv = 1.f / lrun;
    float i4[4];
    #pragma unroll
    for (int r = 0; r < 4; ++r) i4[r] = __shfl(inv, g * 4 + r);
    #pragma unroll
    for (int dt = 0; dt < 4; ++dt) {
        #pragma unroll
        for (int r = 0; r < 4; ++r) {
            const int row = qt * QBLK + w * 16 + g * 4 + r;
            Ob[(size_t)row * ROWS + dt * 16 + q16] = oacc[dt][r] * i4[r];
        }
    }
}

extern "C" void kernel_launch(void* const* d_in, const int* in_sizes, int n_in,
                              void* d_out, int out_size, void* d_ws, size_t ws_size,
                              hipStream_t stream) {
    (void)in_sizes; (void)n_in; (void)out_size; (void)ws_size;
    const float* Q = (const float*)d_in[0];
    const float* K = (const float*)d_in[1];
    const float* V = (const float*)d_in[2];
    // d_in[3] = causal mask (fixed triu k=1) -> handled analytically in-kernel.
    float* O = (float*)d_out;

    __bf16* Kbf = (__bf16*)d_ws;                                   // 8 MB
    __bf16* Vbf = (__bf16*)((char*)d_ws + (size_t)32 * 2048 * 64 * 2);  // 8 MB

    conv_k<<<dim3(1024), dim3(256), 0, stream>>>(K, Kbf);
    conv_v<<<dim3(32, 32), dim3(256), 0, stream>>>(V, Vbf);
    fuzzy_attn_mfma<<<dim3(512), dim3(512), 0, stream>>>(Q, Kbf, Vbf, O);
}